// Round 12
// baseline (125.817 us; speedup 1.0000x reference)
//
#include <hip/hip_runtime.h>
#include <hip/hip_bf16.h>

constexpr int NB   = 32;
constexpr int NENV = 8;
constexpr int F0   = 16;
constexpr int F1   = 32;
constexpr int D    = 256;
constexpr int PAIRS = 128 * 64;   // 8192
constexpr float CUT = 5.0f;
constexpr int RSTR = 272;         // res-row stride in ushorts (544 B: 2-way banks)

typedef float f32x4 __attribute__((ext_vector_type(4)));
typedef short s16x8 __attribute__((ext_vector_type(8)));

__device__ __forceinline__ float fast_rcp(float x) { return __builtin_amdgcn_rcpf(x); }
__device__ __forceinline__ float silu(float a) {
  return a * fast_rcp(1.0f + __expf(-a));
}
__device__ __forceinline__ float fast_tanh(float t) {
  return 1.0f - 2.0f * fast_rcp(__expf(2.0f * t) + 1.0f);
}
// gfx950 single-instruction packed fp32->bf16 (RNE)
__device__ __forceinline__ unsigned int cvt_pk_bf16(float a, float b) {
  unsigned int r;
  asm("v_cvt_pk_bf16_f32 %0, %1, %2" : "=v"(r) : "v"(a), "v"(b));
  return r;
}
__device__ __forceinline__ unsigned short f2bf(float f) {
  return (unsigned short)(cvt_pk_bf16(f, f) & 0xffffu);
}

// ---------------------------------------------------------------------------
// r26 = r23 (verified 112.9 us, absmax 0.09375) + register-pipelined tail.
//
// r24/r25 POST-MORTEM: the LDS-staged tail (union overlay of dead phase-1/2
// buffers) failed twice with wrong-numerics (15.77, then 2.73 after the
// verified w*272 read-index fix). The staging algebra was re-checked with
// concrete examples and is consistent; the residual failure is not
// localizable at source level (suspect: union type-punning uint4-store /
// s16x8-load interaction). Per session discipline (r15-r20 lesson), the
// structure is ABANDONED; this kernel reverts to r23's exact body.
//
// The safe replacement for the same latency problem: the tail's 256 strided
// dword loads were consumed immediately (VGPR=52 -> minimal live set ->
// ~200cy L2 latency exposed per chain). Here each ks-iteration's 32 floats
// are loaded into a named ping-pong buffer (bufA/bufB, static indexing only)
// one iteration ahead of the cvt+MFMA that consumes them. Same addresses,
// same values, same cvt_pk words, same acc/ks/nt order -> bit-identical
// output; only issue order changes. No LDS, no union, no lane remapping.
//
// HARNESS LAUNCH CONVENTION (empirical, r15-r20): single dispatch only, no
// d_ws, no module statics, block size 256. Grid size is respected.
// ---------------------------------------------------------------------------
__global__ __launch_bounds__(256)
void moon_fused(
    const float* __restrict__ r,            // [8192,3]
    const float* __restrict__ r_nb,         // [8192,32,3]
    const float* __restrict__ ee_scales,    // [8]
    const float* __restrict__ ee_kernel,    // [4,16]
    const float* __restrict__ ee_bias,      // [16]
    const float* __restrict__ beta_kernel,  // [24,32]
    const float* __restrict__ beta_bias,    // [32]
    const float* __restrict__ gamma_kernel, // [32,256]
    const float* __restrict__ dense1_kernel,// [4,256]
    const float* __restrict__ dense1_bias,  // [256]
    const float* __restrict__ out_kernel,   // [256,256] (W[k][c], read in tail)
    const float* __restrict__ out_bias,     // [256]
    float* __restrict__ out)                // [8192,256]
{
  __shared__ unsigned short s_ghT[4][D * 8];    // [kslot g][d][8] bf16 (16384 B)
  __shared__ unsigned short s_hb[8][4][NB * 8]; // [pair][g][row][8] hen->beta (16384 B)
  __shared__ unsigned short s_inph[8][RSTR];    // [pair]: inp A-frags (first 256),
                                                // OVERLAID by res rows stride 272 (4352 B)
  __shared__ unsigned int s_d1a[2 * D];         // d1k frag words 0,1 (2048 B)
  __shared__ unsigned int s_d1b[D];             // d1k frag word 2   (1024 B)
  __shared__ float s_is2[NENV];                 // (32 B)
  // total: 40,224 B -> granule 40,448 -> 4 blocks/CU

  const int tid = threadIdx.x;
  const int w   = tid >> 6;                 // wave 0..3; wave w owns pairs 2w, 2w+1
  const int l   = tid & 63;
  const int be0 = blockIdx.x * 8;

  // ---- staging: envelope scales (exact divide preserved) ----
  if (tid < 8) { float s = ee_scales[tid]; s_is2[tid] = 1.0f / (s * s); }

  // ---- staging: gamma -> bf16 transposed, k-chunked (thread t owns row d=t) ----
  {
    const int d = tid;
    unsigned int pk[16];
    #pragma unroll
    for (int k2 = 0; k2 < 16; ++k2)
      pk[k2] = cvt_pk_bf16(gamma_kernel[(2 * k2 + 0) * D + d],
                           gamma_kernel[(2 * k2 + 1) * D + d]);
    #pragma unroll
    for (int g = 0; g < 4; ++g)
      *(uint4*)&s_ghT[g][d * 8] = make_uint4(pk[4*g], pk[4*g+1], pk[4*g+2], pk[4*g+3]);
  }
  // ---- staging: d1k frag words, PRE-SCALED by 0.25 (replication cancel; exact) ----
  {
    const int d = tid;
    unsigned int p0 = cvt_pk_bf16(0.25f * dense1_kernel[0 * D + d],
                                  0.25f * dense1_kernel[1 * D + d]);
    unsigned int p1 = cvt_pk_bf16(0.25f * dense1_kernel[2 * D + d],
                                  0.25f * dense1_kernel[3 * D + d]);
    unsigned int p2 = cvt_pk_bf16(0.25f * dense1_bias[d], 0.0f);  // k=4; k=5..7 zero
    s_d1a[2 * d + 0] = p0;
    s_d1a[2 * d + 1] = p1;
    s_d1b[d] = p2;
  }

  __syncthreads();

  const int li = l & 15;          // col-within-tile
  const int g  = l >> 4;          // k-chunk / C-row group

  // ---- phase 1: per-neighbor features for this lane's pair (2 pairs/wave).
  //      ee_kernel/ee_bias read directly (uniform -> scalar loads); fcut kept
  //      in a register for shfl-based distribution in beta. ----
  float my_fcut;
  {
    const int ph = l >> 5;       // which of the wave's two pairs
    const int n  = l & 31;
    const int p  = w * 2 + ph;   // pair-in-block 0..7
    const int bep = be0 + p;
    float rx = r[bep * 3 + 0];
    float ry = r[bep * 3 + 1];
    float rz = r[bep * 3 + 2];
    const float* rn = r_nb + (bep * NB + n) * 3;
    float dx = rn[0] - rx;
    float dy = rn[1] - ry;
    float dz = rn[2] - rz;
    float d2 = dx * dx + dy * dy + dz * dz;
    float dist = sqrtf(d2);
    float feats[4] = {dist, dx, dy, dz};
    float h[16];
    #pragma unroll
    for (int j = 0; j < 16; ++j) {
      float t = ee_bias[j];
      #pragma unroll
      for (int i = 0; i < 4; ++i) t += feats[i] * ee_kernel[i * F0 + j];
      h[j] = fast_tanh(t);
    }
    unsigned int hp0 = cvt_pk_bf16(h[0], h[1]);
    unsigned int hp1 = cvt_pk_bf16(h[2], h[3]);
    unsigned int hp2 = cvt_pk_bf16(h[4], h[5]);
    unsigned int hp3 = cvt_pk_bf16(h[6], h[7]);
    unsigned int hp4 = cvt_pk_bf16(h[8], h[9]);
    unsigned int hp5 = cvt_pk_bf16(h[10], h[11]);
    unsigned int hp6 = cvt_pk_bf16(h[12], h[13]);
    unsigned int hp7 = cvt_pk_bf16(h[14], h[15]);
    *(uint4*)&s_hb[p][0][n * 8] = make_uint4(hp0, hp1, hp2, hp3);
    *(uint4*)&s_hb[p][1][n * 8] = make_uint4(hp4, hp5, hp6, hp7);
    *(uint4*)&s_hb[p][3][n * 8] = make_uint4(0x3F80u, 0u, 0u, 0u);
    float env[NENV];
    #pragma unroll
    for (int s = 0; s < NENV; ++s) env[s] = __expf(-d2 * s_is2[s]);
    unsigned int e0 = cvt_pk_bf16(env[0], env[1]);
    unsigned int e1 = cvt_pk_bf16(env[2], env[3]);
    unsigned int e2 = cvt_pk_bf16(env[4], env[5]);
    unsigned int e3 = cvt_pk_bf16(env[6], env[7]);
    *(uint4*)&s_hb[p][2][n * 8] = make_uint4(e0, e1, e2, e3);
    float lp  = log1pf(dist);
    float inv = lp / dist;
    unsigned int q0 = cvt_pk_bf16(lp, dx * inv);
    unsigned int q1 = cvt_pk_bf16(dy * inv, dz * inv);
    *(uint4*)&s_inph[p][n * 8] = make_uint4(q0, q1, 0x3F80u, 0u);
    float xc = dist * (1.0f / CUT);
    my_fcut = (xc < 1.0f)
            ? 0.5f * (__cosf(3.14159265358979323846f * xc) + 1.0f)
            : 0.0f;
  }

  // ---- beta B-frags from global (pair-independent; same cvt sequence as the
  //      old LDS staging -> bit-identical). Lane holds chunk g, cols li/16+li. ----
  s16x8 bb0, bb1;
  {
    union { s16x8 v; unsigned int u[4]; } u0, u1;
    if (g < 3) {
      const float* bk0 = beta_kernel + (g * 8) * F1 + li;
      #pragma unroll
      for (int jj = 0; jj < 4; ++jj) {
        u0.u[jj] = cvt_pk_bf16(bk0[(2 * jj) * F1],      bk0[(2 * jj + 1) * F1]);
        u1.u[jj] = cvt_pk_bf16(bk0[(2 * jj) * F1 + 16], bk0[(2 * jj + 1) * F1 + 16]);
      }
    } else {
      u0.u[0] = cvt_pk_bf16(beta_bias[li], 0.0f);      u0.u[1] = u0.u[2] = u0.u[3] = 0u;
      u1.u[0] = cvt_pk_bf16(beta_bias[16 + li], 0.0f); u1.u[1] = u1.u[2] = u1.u[3] = 0u;
    }
    bb0 = u0.v; bb1 = u1.v;
  }

  // ---- beta via MFMA per pair: beta[n][c] = (hen @ bk + bias) * fcut[n].
  //      Wave-local read-then-overwrite of s_hb (r14-proven, no barrier).
  //      fcut fetched by shfl from the lane that computed it. ----
  auto beta_pair = [&](int p) {
    s16x8 ah0 = *(const s16x8*)&s_hb[p][g][(0 * 16 + li) * 8];
    s16x8 ah1 = *(const s16x8*)&s_hb[p][g][(1 * 16 + li) * 8];
    f32x4 z = {0.f, 0.f, 0.f, 0.f};
    f32x4 c00 = __builtin_amdgcn_mfma_f32_16x16x32_bf16(ah0, bb0, z, 0, 0, 0);
    f32x4 c01 = __builtin_amdgcn_mfma_f32_16x16x32_bf16(ah0, bb1, z, 0, 0, 0);
    f32x4 c10 = __builtin_amdgcn_mfma_f32_16x16x32_bf16(ah1, bb0, z, 0, 0, 0);
    f32x4 c11 = __builtin_amdgcn_mfma_f32_16x16x32_bf16(ah1, bb1, z, 0, 0, 0);
    const int cl = li >> 3;
    const int sl = li & 7;
    const int base = (p & 1) * 32;
    #pragma unroll
    for (int reg = 0; reg < 4; ++reg) {
      int row0 = g * 4 + reg;
      int row1 = 16 + g * 4 + reg;
      float fc0 = __shfl(my_fcut, base + row0);
      float fc1 = __shfl(my_fcut, base + row1);
      s_hb[p][cl    ][row0 * 8 + sl] = f2bf(c00[reg] * fc0);
      s_hb[p][2 + cl][row0 * 8 + sl] = f2bf(c01[reg] * fc0);
      s_hb[p][cl    ][row1 * 8 + sl] = f2bf(c10[reg] * fc1);
      s_hb[p][2 + cl][row1 * 8 + sl] = f2bf(c11[reg] * fc1);
    }
  };
  beta_pair(w * 2 + 0);
  beta_pair(w * 2 + 1);

  // ---- phase 2, PAIR-FUSED: one nt loop; gamma/d1k frags loaded once and
  //      shared by both pairs. A-frags register-consumed FIRST, then res rows
  //      overwrite the pairs' own s_inph rows (same-wave program-order DS;
  //      rows are pair-disjoint). Per-output accumulation order == r23. ----
  unsigned short* resall = &s_inph[0][0];   // [pair][RSTR] overlay
  {
    const int p0 = w * 2 + 0;
    const int p1 = w * 2 + 1;
    s16x8 a0_0 = *(const s16x8*)&s_hb[p0][g][(0 * 16 + li) * 8];
    s16x8 a1_0 = *(const s16x8*)&s_hb[p0][g][(1 * 16 + li) * 8];
    s16x8 ai0_0 = *(const s16x8*)&s_inph[p0][(0 * 16 + li) * 8];
    s16x8 ai1_0 = *(const s16x8*)&s_inph[p0][(1 * 16 + li) * 8];
    s16x8 a0_1 = *(const s16x8*)&s_hb[p1][g][(0 * 16 + li) * 8];
    s16x8 a1_1 = *(const s16x8*)&s_hb[p1][g][(1 * 16 + li) * 8];
    s16x8 ai0_1 = *(const s16x8*)&s_inph[p1][(0 * 16 + li) * 8];
    s16x8 ai1_1 = *(const s16x8*)&s_inph[p1][(1 * 16 + li) * 8];

    #pragma unroll 4
    for (int nt = 0; nt < 16; ++nt) {
      const int d = nt * 16 + li;
      s16x8 b = *(const s16x8*)&s_ghT[g][d * 8];
      union { s16x8 v; unsigned int u[4]; } ud;
      ud.u[0] = s_d1a[2 * d + 0];
      ud.u[1] = s_d1a[2 * d + 1];
      ud.u[2] = s_d1b[d];
      ud.u[3] = 0u;
      f32x4 z = {0.f, 0.f, 0.f, 0.f};
      // pair 0
      {
        f32x4 c0 = __builtin_amdgcn_mfma_f32_16x16x32_bf16(a0_0, b, z, 0, 0, 0);
        f32x4 c1 = __builtin_amdgcn_mfma_f32_16x16x32_bf16(a1_0, b, z, 0, 0, 0);
        f32x4 f0 = __builtin_amdgcn_mfma_f32_16x16x32_bf16(ai0_0, ud.v, z, 0, 0, 0);
        f32x4 f1 = __builtin_amdgcn_mfma_f32_16x16x32_bf16(ai1_0, ud.v, z, 0, 0, 0);
        float pv = 0.f;
        #pragma unroll
        for (int reg = 0; reg < 4; ++reg) {
          pv += silu(f0[reg]) * c0[reg];
          pv += silu(f1[reg]) * c1[reg];
        }
        pv += __shfl_xor(pv, 16);
        pv += __shfl_xor(pv, 32);
        if (g == (nt & 3)) resall[p0 * RSTR + nt * 16 + li] = f2bf(pv);
      }
      // pair 1
      {
        f32x4 c0 = __builtin_amdgcn_mfma_f32_16x16x32_bf16(a0_1, b, z, 0, 0, 0);
        f32x4 c1 = __builtin_amdgcn_mfma_f32_16x16x32_bf16(a1_1, b, z, 0, 0, 0);
        f32x4 f0 = __builtin_amdgcn_mfma_f32_16x16x32_bf16(ai0_1, ud.v, z, 0, 0, 0);
        f32x4 f1 = __builtin_amdgcn_mfma_f32_16x16x32_bf16(ai1_1, ud.v, z, 0, 0, 0);
        float pv = 0.f;
        #pragma unroll
        for (int reg = 0; reg < 4; ++reg) {
          pv += silu(f0[reg]) * c0[reg];
          pv += silu(f1[reg]) * c1[reg];
        }
        pv += __shfl_xor(pv, 16);
        pv += __shfl_xor(pv, 32);
        if (g == (nt & 3)) resall[p1 * RSTR + nt * 16 + li] = f2bf(pv);
      }
    }
  }

  __syncthreads();   // all 8 pairs' res rows needed by every wave in the tail

  // ---- tail: out[be0+0..7, :] = silu(res @ W + b). A rows = res[li&7]
  //      (8 real pairs, 2x replication); C rows g*4+reg written for g<2.
  //      B-frags built from fp32 out_kernel via cvt_pk_bf16 with a REGISTER
  //      SOFTWARE PIPELINE: iteration ks+1's 32 floats load into the named
  //      ping-pong buffer while ks's cvt+MFMA runs. Same addresses, values,
  //      cvt words, and acc/ks/nt order as r23 -> bit-identical. ----
  {
    const int col0 = w * 64;
    float bi[4];
    #pragma unroll
    for (int nt = 0; nt < 4; ++nt) bi[nt] = out_bias[col0 + nt * 16 + li];

    f32x4 acc[4] = {{0.f,0.f,0.f,0.f},{0.f,0.f,0.f,0.f},{0.f,0.f,0.f,0.f},{0.f,0.f,0.f,0.f}};
    const unsigned short* arow = resall + (li & 7) * RSTR + g * 8;
    const float* wp = out_kernel + col0 + li;   // lane's base column

    float bufA[4][8], bufB[4][8];

    auto load32 = [&](int ks, float (&buf)[4][8]) {
      const float* wk0 = wp + (ks * 32 + g * 8) * D;   // W[k0][c0]
      #pragma unroll
      for (int nt = 0; nt < 4; ++nt) {
        const float* wq = wk0 + nt * 16;
        #pragma unroll
        for (int jj = 0; jj < 8; ++jj)
          buf[nt][jj] = wq[jj * D];
      }
    };
    auto mfma_ks = [&](int ks, const float (&buf)[4][8]) {
      s16x8 a = *(const s16x8*)(arow + ks * 32);
      #pragma unroll
      for (int nt = 0; nt < 4; ++nt) {
        union { s16x8 v; unsigned int u[4]; } ub;
        #pragma unroll
        for (int jj = 0; jj < 4; ++jj)
          ub.u[jj] = cvt_pk_bf16(buf[nt][2 * jj], buf[nt][2 * jj + 1]);
        acc[nt] = __builtin_amdgcn_mfma_f32_16x16x32_bf16(a, ub.v, acc[nt], 0, 0, 0);
      }
    };

    load32(0, bufA);
    #pragma unroll
    for (int kk = 0; kk < 4; ++kk) {
      load32(2 * kk + 1, bufB);           // prefetch odd ks
      mfma_ks(2 * kk + 0, bufA);          // consume even ks
      if (kk < 3) load32(2 * kk + 2, bufA);  // prefetch next even ks
      mfma_ks(2 * kk + 1, bufB);          // consume odd ks
    }

    if (g < 2) {
      #pragma unroll
      for (int nt = 0; nt < 4; ++nt) {
        #pragma unroll
        for (int reg = 0; reg < 4; ++reg) {
          out[(be0 + g * 4 + reg) * D + col0 + nt * 16 + li] = silu(acc[nt][reg] + bi[nt]);
        }
      }
    }
  }
}

extern "C" void kernel_launch(void* const* d_in, const int* in_sizes, int n_in,
                              void* d_out, int out_size, void* d_ws, size_t ws_size,
                              hipStream_t stream) {
  const float* r            = (const float*)d_in[0];
  const float* r_nb         = (const float*)d_in[1];
  const float* ee_scales    = (const float*)d_in[2];
  const float* ee_kernel    = (const float*)d_in[3];
  const float* ee_bias      = (const float*)d_in[4];
  const float* beta_kernel  = (const float*)d_in[5];
  const float* beta_bias    = (const float*)d_in[6];
  const float* gamma_kernel = (const float*)d_in[7];
  const float* dense1_kernel= (const float*)d_in[8];
  const float* dense1_bias  = (const float*)d_in[9];
  const float* out_kernel   = (const float*)d_in[10];
  const float* out_bias     = (const float*)d_in[11];
  float* out = (float*)d_out;
  (void)d_ws; (void)ws_size;

  // single dispatch; 256 threads (harness convention); 8 pairs/block;
  // grid 1024 = 4 blocks/CU resident (LDS 40,224 B) -> one balanced round
  hipLaunchKernelGGL(moon_fused, dim3(PAIRS / 8), dim3(256), 0, stream,
                     r, r_nb, ee_scales, ee_kernel, ee_bias,
                     beta_kernel, beta_bias, gamma_kernel,
                     dense1_kernel, dense1_bias, out_kernel, out_bias, out);
}

// Round 13
// 111.463 us; speedup vs baseline: 1.1288x; 1.1288x over previous
//
#include <hip/hip_runtime.h>
#include <hip/hip_bf16.h>

constexpr int NB   = 32;
constexpr int NENV = 8;
constexpr int F0   = 16;
constexpr int F1   = 32;
constexpr int D    = 256;
constexpr int PAIRS = 128 * 64;   // 8192
constexpr float CUT = 5.0f;
constexpr int RSTR = 272;         // res-row stride in ushorts (544 B: 2-way banks)

typedef float f32x4 __attribute__((ext_vector_type(4)));
typedef short s16x8 __attribute__((ext_vector_type(8)));

__device__ __forceinline__ float fast_rcp(float x) { return __builtin_amdgcn_rcpf(x); }
__device__ __forceinline__ float silu(float a) {
  return a * fast_rcp(1.0f + __expf(-a));
}
__device__ __forceinline__ float fast_tanh(float t) {
  return 1.0f - 2.0f * fast_rcp(__expf(2.0f * t) + 1.0f);
}
// gfx950 single-instruction packed fp32->bf16 (RNE)
__device__ __forceinline__ unsigned int cvt_pk_bf16(float a, float b) {
  unsigned int r;
  asm("v_cvt_pk_bf16_f32 %0, %1, %2" : "=v"(r) : "v"(a), "v"(b));
  return r;
}
__device__ __forceinline__ unsigned short f2bf(float f) {
  return (unsigned short)(cvt_pk_bf16(f, f) & 0xffffu);
}

// ---------------------------------------------------------------------------
// r27 = EXACT REVERT to r23, the session's verified best (112.9 us, dispatch
// 41.5 us, absmax 0.09375).
//
// FINAL POST-MORTEM of the tail-latency attack (r24/r25/r26):
//  - r24/r25 (LDS-staged tail via union overlay): wrong numerics twice
//    (15.77; 2.73 after the verified w*272 read-index fix); residual bug not
//    localizable at source level.
//  - r26 (register ping-pong pipeline): compiler kept VGPR=52 (launch-bounds
//    allocation) and spilled the 64-float buffers to scratch -> dispatch
//    41.5 -> 56 us. The assumed mechanism (register prefetch) never
//    materialized in codegen.
// All three source-level forms of hiding the tail's load latency are
// exhausted without disasm-in-the-loop; r23 stands.
//
// r23 structure: 8 pairs/block at 256 threads (4 waves x 2 pairs), single
// dispatch; LDS 40,224 B -> 4 blocks/CU (one balanced round at grid 1024);
// res-overlay stride 272 (tail ds_read 2-way banks, free); phase-2
// pair-fused (gamma/d1k frags loaded once, shared by both pairs).
//
// HARNESS LAUNCH CONVENTION (empirical, r15-r20): single dispatch only, no
// d_ws, no module statics, block size 256. Grid size is respected.
// ---------------------------------------------------------------------------
__global__ __launch_bounds__(256)
void moon_fused(
    const float* __restrict__ r,            // [8192,3]
    const float* __restrict__ r_nb,         // [8192,32,3]
    const float* __restrict__ ee_scales,    // [8]
    const float* __restrict__ ee_kernel,    // [4,16]
    const float* __restrict__ ee_bias,      // [16]
    const float* __restrict__ beta_kernel,  // [24,32]
    const float* __restrict__ beta_bias,    // [32]
    const float* __restrict__ gamma_kernel, // [32,256]
    const float* __restrict__ dense1_kernel,// [4,256]
    const float* __restrict__ dense1_bias,  // [256]
    const float* __restrict__ out_kernel,   // [256,256] (W[k][c], read in tail)
    const float* __restrict__ out_bias,     // [256]
    float* __restrict__ out)                // [8192,256]
{
  __shared__ unsigned short s_ghT[4][D * 8];    // [kslot g][d][8] bf16 (16384 B)
  __shared__ unsigned short s_hb[8][4][NB * 8]; // [pair][g][row][8] hen->beta (16384 B)
  __shared__ unsigned short s_inph[8][RSTR];    // [pair]: inp A-frags (first 256),
                                                // OVERLAID by res rows stride 272 (4352 B)
  __shared__ unsigned int s_d1a[2 * D];         // d1k frag words 0,1 (2048 B)
  __shared__ unsigned int s_d1b[D];             // d1k frag word 2   (1024 B)
  __shared__ float s_is2[NENV];                 // (32 B)
  // total: 40,224 B -> granule 40,448 -> 4 blocks/CU

  const int tid = threadIdx.x;
  const int w   = tid >> 6;                 // wave 0..3; wave w owns pairs 2w, 2w+1
  const int l   = tid & 63;
  const int be0 = blockIdx.x * 8;

  // ---- staging: envelope scales (exact divide preserved) ----
  if (tid < 8) { float s = ee_scales[tid]; s_is2[tid] = 1.0f / (s * s); }

  // ---- staging: gamma -> bf16 transposed, k-chunked (thread t owns row d=t) ----
  {
    const int d = tid;
    unsigned int pk[16];
    #pragma unroll
    for (int k2 = 0; k2 < 16; ++k2)
      pk[k2] = cvt_pk_bf16(gamma_kernel[(2 * k2 + 0) * D + d],
                           gamma_kernel[(2 * k2 + 1) * D + d]);
    #pragma unroll
    for (int g = 0; g < 4; ++g)
      *(uint4*)&s_ghT[g][d * 8] = make_uint4(pk[4*g], pk[4*g+1], pk[4*g+2], pk[4*g+3]);
  }
  // ---- staging: d1k frag words, PRE-SCALED by 0.25 (replication cancel; exact) ----
  {
    const int d = tid;
    unsigned int p0 = cvt_pk_bf16(0.25f * dense1_kernel[0 * D + d],
                                  0.25f * dense1_kernel[1 * D + d]);
    unsigned int p1 = cvt_pk_bf16(0.25f * dense1_kernel[2 * D + d],
                                  0.25f * dense1_kernel[3 * D + d]);
    unsigned int p2 = cvt_pk_bf16(0.25f * dense1_bias[d], 0.0f);  // k=4; k=5..7 zero
    s_d1a[2 * d + 0] = p0;
    s_d1a[2 * d + 1] = p1;
    s_d1b[d] = p2;
  }

  __syncthreads();

  const int li = l & 15;          // col-within-tile
  const int g  = l >> 4;          // k-chunk / C-row group

  // ---- phase 1: per-neighbor features for this lane's pair (2 pairs/wave).
  //      ee_kernel/ee_bias read directly (uniform -> scalar loads); fcut kept
  //      in a register for shfl-based distribution in beta. ----
  float my_fcut;
  {
    const int ph = l >> 5;       // which of the wave's two pairs
    const int n  = l & 31;
    const int p  = w * 2 + ph;   // pair-in-block 0..7
    const int bep = be0 + p;
    float rx = r[bep * 3 + 0];
    float ry = r[bep * 3 + 1];
    float rz = r[bep * 3 + 2];
    const float* rn = r_nb + (bep * NB + n) * 3;
    float dx = rn[0] - rx;
    float dy = rn[1] - ry;
    float dz = rn[2] - rz;
    float d2 = dx * dx + dy * dy + dz * dz;
    float dist = sqrtf(d2);
    float feats[4] = {dist, dx, dy, dz};
    float h[16];
    #pragma unroll
    for (int j = 0; j < 16; ++j) {
      float t = ee_bias[j];
      #pragma unroll
      for (int i = 0; i < 4; ++i) t += feats[i] * ee_kernel[i * F0 + j];
      h[j] = fast_tanh(t);
    }
    unsigned int hp0 = cvt_pk_bf16(h[0], h[1]);
    unsigned int hp1 = cvt_pk_bf16(h[2], h[3]);
    unsigned int hp2 = cvt_pk_bf16(h[4], h[5]);
    unsigned int hp3 = cvt_pk_bf16(h[6], h[7]);
    unsigned int hp4 = cvt_pk_bf16(h[8], h[9]);
    unsigned int hp5 = cvt_pk_bf16(h[10], h[11]);
    unsigned int hp6 = cvt_pk_bf16(h[12], h[13]);
    unsigned int hp7 = cvt_pk_bf16(h[14], h[15]);
    *(uint4*)&s_hb[p][0][n * 8] = make_uint4(hp0, hp1, hp2, hp3);
    *(uint4*)&s_hb[p][1][n * 8] = make_uint4(hp4, hp5, hp6, hp7);
    *(uint4*)&s_hb[p][3][n * 8] = make_uint4(0x3F80u, 0u, 0u, 0u);
    float env[NENV];
    #pragma unroll
    for (int s = 0; s < NENV; ++s) env[s] = __expf(-d2 * s_is2[s]);
    unsigned int e0 = cvt_pk_bf16(env[0], env[1]);
    unsigned int e1 = cvt_pk_bf16(env[2], env[3]);
    unsigned int e2 = cvt_pk_bf16(env[4], env[5]);
    unsigned int e3 = cvt_pk_bf16(env[6], env[7]);
    *(uint4*)&s_hb[p][2][n * 8] = make_uint4(e0, e1, e2, e3);
    float lp  = log1pf(dist);
    float inv = lp / dist;
    unsigned int q0 = cvt_pk_bf16(lp, dx * inv);
    unsigned int q1 = cvt_pk_bf16(dy * inv, dz * inv);
    *(uint4*)&s_inph[p][n * 8] = make_uint4(q0, q1, 0x3F80u, 0u);
    float xc = dist * (1.0f / CUT);
    my_fcut = (xc < 1.0f)
            ? 0.5f * (__cosf(3.14159265358979323846f * xc) + 1.0f)
            : 0.0f;
  }

  // ---- beta B-frags from global (pair-independent; same cvt sequence as the
  //      old LDS staging -> bit-identical). Lane holds chunk g, cols li/16+li. ----
  s16x8 bb0, bb1;
  {
    union { s16x8 v; unsigned int u[4]; } u0, u1;
    if (g < 3) {
      const float* bk0 = beta_kernel + (g * 8) * F1 + li;
      #pragma unroll
      for (int jj = 0; jj < 4; ++jj) {
        u0.u[jj] = cvt_pk_bf16(bk0[(2 * jj) * F1],      bk0[(2 * jj + 1) * F1]);
        u1.u[jj] = cvt_pk_bf16(bk0[(2 * jj) * F1 + 16], bk0[(2 * jj + 1) * F1 + 16]);
      }
    } else {
      u0.u[0] = cvt_pk_bf16(beta_bias[li], 0.0f);      u0.u[1] = u0.u[2] = u0.u[3] = 0u;
      u1.u[0] = cvt_pk_bf16(beta_bias[16 + li], 0.0f); u1.u[1] = u1.u[2] = u1.u[3] = 0u;
    }
    bb0 = u0.v; bb1 = u1.v;
  }

  // ---- beta via MFMA per pair: beta[n][c] = (hen @ bk + bias) * fcut[n].
  //      Wave-local read-then-overwrite of s_hb (r14-proven, no barrier).
  //      fcut fetched by shfl from the lane that computed it. ----
  auto beta_pair = [&](int p) {
    s16x8 ah0 = *(const s16x8*)&s_hb[p][g][(0 * 16 + li) * 8];
    s16x8 ah1 = *(const s16x8*)&s_hb[p][g][(1 * 16 + li) * 8];
    f32x4 z = {0.f, 0.f, 0.f, 0.f};
    f32x4 c00 = __builtin_amdgcn_mfma_f32_16x16x32_bf16(ah0, bb0, z, 0, 0, 0);
    f32x4 c01 = __builtin_amdgcn_mfma_f32_16x16x32_bf16(ah0, bb1, z, 0, 0, 0);
    f32x4 c10 = __builtin_amdgcn_mfma_f32_16x16x32_bf16(ah1, bb0, z, 0, 0, 0);
    f32x4 c11 = __builtin_amdgcn_mfma_f32_16x16x32_bf16(ah1, bb1, z, 0, 0, 0);
    const int cl = li >> 3;
    const int sl = li & 7;
    const int base = (p & 1) * 32;
    #pragma unroll
    for (int reg = 0; reg < 4; ++reg) {
      int row0 = g * 4 + reg;
      int row1 = 16 + g * 4 + reg;
      float fc0 = __shfl(my_fcut, base + row0);
      float fc1 = __shfl(my_fcut, base + row1);
      s_hb[p][cl    ][row0 * 8 + sl] = f2bf(c00[reg] * fc0);
      s_hb[p][2 + cl][row0 * 8 + sl] = f2bf(c01[reg] * fc0);
      s_hb[p][cl    ][row1 * 8 + sl] = f2bf(c10[reg] * fc1);
      s_hb[p][2 + cl][row1 * 8 + sl] = f2bf(c11[reg] * fc1);
    }
  };
  beta_pair(w * 2 + 0);
  beta_pair(w * 2 + 1);

  // ---- phase 2, PAIR-FUSED: one nt loop; gamma/d1k frags loaded once and
  //      shared by both pairs. A-frags register-consumed FIRST, then res rows
  //      overwrite the pairs' own s_inph rows (same-wave program-order DS;
  //      rows are pair-disjoint). Per-output accumulation order == r22. ----
  unsigned short* resall = &s_inph[0][0];   // [pair][RSTR] overlay
  {
    const int p0 = w * 2 + 0;
    const int p1 = w * 2 + 1;
    s16x8 a0_0 = *(const s16x8*)&s_hb[p0][g][(0 * 16 + li) * 8];
    s16x8 a1_0 = *(const s16x8*)&s_hb[p0][g][(1 * 16 + li) * 8];
    s16x8 ai0_0 = *(const s16x8*)&s_inph[p0][(0 * 16 + li) * 8];
    s16x8 ai1_0 = *(const s16x8*)&s_inph[p0][(1 * 16 + li) * 8];
    s16x8 a0_1 = *(const s16x8*)&s_hb[p1][g][(0 * 16 + li) * 8];
    s16x8 a1_1 = *(const s16x8*)&s_hb[p1][g][(1 * 16 + li) * 8];
    s16x8 ai0_1 = *(const s16x8*)&s_inph[p1][(0 * 16 + li) * 8];
    s16x8 ai1_1 = *(const s16x8*)&s_inph[p1][(1 * 16 + li) * 8];

    #pragma unroll 4
    for (int nt = 0; nt < 16; ++nt) {
      const int d = nt * 16 + li;
      s16x8 b = *(const s16x8*)&s_ghT[g][d * 8];
      union { s16x8 v; unsigned int u[4]; } ud;
      ud.u[0] = s_d1a[2 * d + 0];
      ud.u[1] = s_d1a[2 * d + 1];
      ud.u[2] = s_d1b[d];
      ud.u[3] = 0u;
      f32x4 z = {0.f, 0.f, 0.f, 0.f};
      // pair 0
      {
        f32x4 c0 = __builtin_amdgcn_mfma_f32_16x16x32_bf16(a0_0, b, z, 0, 0, 0);
        f32x4 c1 = __builtin_amdgcn_mfma_f32_16x16x32_bf16(a1_0, b, z, 0, 0, 0);
        f32x4 f0 = __builtin_amdgcn_mfma_f32_16x16x32_bf16(ai0_0, ud.v, z, 0, 0, 0);
        f32x4 f1 = __builtin_amdgcn_mfma_f32_16x16x32_bf16(ai1_0, ud.v, z, 0, 0, 0);
        float pv = 0.f;
        #pragma unroll
        for (int reg = 0; reg < 4; ++reg) {
          pv += silu(f0[reg]) * c0[reg];
          pv += silu(f1[reg]) * c1[reg];
        }
        pv += __shfl_xor(pv, 16);
        pv += __shfl_xor(pv, 32);
        if (g == (nt & 3)) resall[p0 * RSTR + nt * 16 + li] = f2bf(pv);
      }
      // pair 1
      {
        f32x4 c0 = __builtin_amdgcn_mfma_f32_16x16x32_bf16(a0_1, b, z, 0, 0, 0);
        f32x4 c1 = __builtin_amdgcn_mfma_f32_16x16x32_bf16(a1_1, b, z, 0, 0, 0);
        f32x4 f0 = __builtin_amdgcn_mfma_f32_16x16x32_bf16(ai0_1, ud.v, z, 0, 0, 0);
        f32x4 f1 = __builtin_amdgcn_mfma_f32_16x16x32_bf16(ai1_1, ud.v, z, 0, 0, 0);
        float pv = 0.f;
        #pragma unroll
        for (int reg = 0; reg < 4; ++reg) {
          pv += silu(f0[reg]) * c0[reg];
          pv += silu(f1[reg]) * c1[reg];
        }
        pv += __shfl_xor(pv, 16);
        pv += __shfl_xor(pv, 32);
        if (g == (nt & 3)) resall[p1 * RSTR + nt * 16 + li] = f2bf(pv);
      }
    }
  }

  __syncthreads();   // all 8 pairs' res rows needed by every wave in the tail

  // ---- tail: out[be0+0..7, :] = silu(res @ W + b). A rows = res[li&7]
  //      (8 real pairs, 2x replication); C rows g*4+reg written for g<2.
  //      B-frags built directly from fp32 out_kernel via cvt_pk_bf16 --
  //      identical per-element math and accumulation order to r14/r21/r22. ----
  {
    const int col0 = w * 64;
    float bi[4];
    #pragma unroll
    for (int nt = 0; nt < 4; ++nt) bi[nt] = out_bias[col0 + nt * 16 + li];

    f32x4 acc[4] = {{0.f,0.f,0.f,0.f},{0.f,0.f,0.f,0.f},{0.f,0.f,0.f,0.f},{0.f,0.f,0.f,0.f}};
    const unsigned short* arow = resall + (li & 7) * RSTR + g * 8;
    const float* wp = out_kernel + col0 + li;   // lane's base column

    #pragma unroll 2
    for (int ks = 0; ks < 8; ++ks) {
      s16x8 a = *(const s16x8*)(arow + ks * 32);
      const float* wk0 = wp + (ks * 32 + g * 8) * D;   // W[k0][c0]
      #pragma unroll
      for (int nt = 0; nt < 4; ++nt) {
        const float* wq = wk0 + nt * 16;
        union { s16x8 v; unsigned int u[4]; } ub;
        #pragma unroll
        for (int jj = 0; jj < 4; ++jj)
          ub.u[jj] = cvt_pk_bf16(wq[(2 * jj) * D], wq[(2 * jj + 1) * D]);
        acc[nt] = __builtin_amdgcn_mfma_f32_16x16x32_bf16(a, ub.v, acc[nt], 0, 0, 0);
      }
    }
    if (g < 2) {
      #pragma unroll
      for (int nt = 0; nt < 4; ++nt) {
        #pragma unroll
        for (int reg = 0; reg < 4; ++reg) {
          out[(be0 + g * 4 + reg) * D + col0 + nt * 16 + li] = silu(acc[nt][reg] + bi[nt]);
        }
      }
    }
  }
}

extern "C" void kernel_launch(void* const* d_in, const int* in_sizes, int n_in,
                              void* d_out, int out_size, void* d_ws, size_t ws_size,
                              hipStream_t stream) {
  const float* r            = (const float*)d_in[0];
  const float* r_nb         = (const float*)d_in[1];
  const float* ee_scales    = (const float*)d_in[2];
  const float* ee_kernel    = (const float*)d_in[3];
  const float* ee_bias      = (const float*)d_in[4];
  const float* beta_kernel  = (const float*)d_in[5];
  const float* beta_bias    = (const float*)d_in[6];
  const float* gamma_kernel = (const float*)d_in[7];
  const float* dense1_kernel= (const float*)d_in[8];
  const float* dense1_bias  = (const float*)d_in[9];
  const float* out_kernel   = (const float*)d_in[10];
  const float* out_bias     = (const float*)d_in[11];
  float* out = (float*)d_out;
  (void)d_ws; (void)ws_size;

  // single dispatch; 256 threads (harness convention); 8 pairs/block;
  // grid 1024 = 4 blocks/CU resident (LDS 40,224 B) -> one balanced round
  hipLaunchKernelGGL(moon_fused, dim3(PAIRS / 8), dim3(256), 0, stream,
                     r, r_nb, ee_scales, ee_kernel, ee_bias,
                     beta_kernel, beta_bias, gamma_kernel,
                     dense1_kernel, dense1_bias, out_kernel, out_bias, out);
}

// Round 14
// 110.181 us; speedup vs baseline: 1.1419x; 1.0116x over previous
//
#include <hip/hip_runtime.h>
#include <hip/hip_bf16.h>

constexpr int NB   = 32;
constexpr int NENV = 8;
constexpr int F0   = 16;
constexpr int F1   = 32;
constexpr int D    = 256;
constexpr int PAIRS = 128 * 64;   // 8192
constexpr float CUT = 5.0f;
constexpr int RSTR = 272;         // res-row stride in ushorts (544 B: 2-way banks)

typedef float f32x4 __attribute__((ext_vector_type(4)));
typedef short s16x8 __attribute__((ext_vector_type(8)));

__device__ __forceinline__ float fast_rcp(float x) { return __builtin_amdgcn_rcpf(x); }
__device__ __forceinline__ float silu(float a) {
  return a * fast_rcp(1.0f + __expf(-a));
}
__device__ __forceinline__ float fast_tanh(float t) {
  return 1.0f - 2.0f * fast_rcp(__expf(2.0f * t) + 1.0f);
}
// gfx950 single-instruction packed fp32->bf16 (RNE)
__device__ __forceinline__ unsigned int cvt_pk_bf16(float a, float b) {
  unsigned int r;
  asm("v_cvt_pk_bf16_f32 %0, %1, %2" : "=v"(r) : "v"(a), "v"(b));
  return r;
}
__device__ __forceinline__ unsigned short f2bf(float f) {
  return (unsigned short)(cvt_pk_bf16(f, f) & 0xffffu);
}

// ---------------------------------------------------------------------------
// r28 = r23/r27 (verified 111.5 us) + tail register ping-pong, LAMBDA-FREE.
//
// r26 POST-MORTEM (41.5 -> 56 us): the pipeline buffers were passed to
// load32/mfma_ks lambdas as array-REFERENCE parameters -> address taken ->
// mem2reg defeated -> buffers lived in scratch (VGPR stayed 52; the "spill"
// was an un-promoted alloca, rule-#20 class). Fix here:
//  (1) tail written INLINE, no lambdas; ks loop fully unrolled so every
//      buf[ks&1][nt][jj] index is a compile-time constant (promotable);
//  (2) amdgpu_waves_per_eu(4,4) restored (as r14 had) so the allocator may
//      use up to 128 VGPR/wave -- LDS already caps occupancy at 4 waves/SIMD
//      (4 blocks/CU x 4 waves), so the VGPR headroom is free.
// Loads for ks+1 (32 floats) precede ks's cvt+MFMA in program order ->
// ~200cy L2 latency hides under compute. Same addresses, same cvt_pk words,
// same acc/ks/nt order -> bit-identical output.
// SIGNAL: VGPR ~110-130 => promotion worked; VGPR ~52 => failed (revert r27).
//
// r23 structure kept: 8 pairs/block at 256 threads (4 waves x 2 pairs),
// single dispatch; LDS 40,224 B -> 4 blocks/CU (one balanced round at grid
// 1024); res-overlay stride 272; phase-2 pair-fused.
//
// HARNESS LAUNCH CONVENTION (empirical, r15-r20): single dispatch only, no
// d_ws, no module statics, block size 256. Grid size is respected.
// ---------------------------------------------------------------------------
__global__ __launch_bounds__(256)
__attribute__((amdgpu_waves_per_eu(4, 4)))
void moon_fused(
    const float* __restrict__ r,            // [8192,3]
    const float* __restrict__ r_nb,         // [8192,32,3]
    const float* __restrict__ ee_scales,    // [8]
    const float* __restrict__ ee_kernel,    // [4,16]
    const float* __restrict__ ee_bias,      // [16]
    const float* __restrict__ beta_kernel,  // [24,32]
    const float* __restrict__ beta_bias,    // [32]
    const float* __restrict__ gamma_kernel, // [32,256]
    const float* __restrict__ dense1_kernel,// [4,256]
    const float* __restrict__ dense1_bias,  // [256]
    const float* __restrict__ out_kernel,   // [256,256] (W[k][c], read in tail)
    const float* __restrict__ out_bias,     // [256]
    float* __restrict__ out)                // [8192,256]
{
  __shared__ unsigned short s_ghT[4][D * 8];    // [kslot g][d][8] bf16 (16384 B)
  __shared__ unsigned short s_hb[8][4][NB * 8]; // [pair][g][row][8] hen->beta (16384 B)
  __shared__ unsigned short s_inph[8][RSTR];    // [pair]: inp A-frags (first 256),
                                                // OVERLAID by res rows stride 272 (4352 B)
  __shared__ unsigned int s_d1a[2 * D];         // d1k frag words 0,1 (2048 B)
  __shared__ unsigned int s_d1b[D];             // d1k frag word 2   (1024 B)
  __shared__ float s_is2[NENV];                 // (32 B)
  // total: 40,224 B -> granule 40,448 -> 4 blocks/CU

  const int tid = threadIdx.x;
  const int w   = tid >> 6;                 // wave 0..3; wave w owns pairs 2w, 2w+1
  const int l   = tid & 63;
  const int be0 = blockIdx.x * 8;

  // ---- staging: envelope scales (exact divide preserved) ----
  if (tid < 8) { float s = ee_scales[tid]; s_is2[tid] = 1.0f / (s * s); }

  // ---- staging: gamma -> bf16 transposed, k-chunked (thread t owns row d=t) ----
  {
    const int d = tid;
    unsigned int pk[16];
    #pragma unroll
    for (int k2 = 0; k2 < 16; ++k2)
      pk[k2] = cvt_pk_bf16(gamma_kernel[(2 * k2 + 0) * D + d],
                           gamma_kernel[(2 * k2 + 1) * D + d]);
    #pragma unroll
    for (int g = 0; g < 4; ++g)
      *(uint4*)&s_ghT[g][d * 8] = make_uint4(pk[4*g], pk[4*g+1], pk[4*g+2], pk[4*g+3]);
  }
  // ---- staging: d1k frag words, PRE-SCALED by 0.25 (replication cancel; exact) ----
  {
    const int d = tid;
    unsigned int p0 = cvt_pk_bf16(0.25f * dense1_kernel[0 * D + d],
                                  0.25f * dense1_kernel[1 * D + d]);
    unsigned int p1 = cvt_pk_bf16(0.25f * dense1_kernel[2 * D + d],
                                  0.25f * dense1_kernel[3 * D + d]);
    unsigned int p2 = cvt_pk_bf16(0.25f * dense1_bias[d], 0.0f);  // k=4; k=5..7 zero
    s_d1a[2 * d + 0] = p0;
    s_d1a[2 * d + 1] = p1;
    s_d1b[d] = p2;
  }

  __syncthreads();

  const int li = l & 15;          // col-within-tile
  const int g  = l >> 4;          // k-chunk / C-row group

  // ---- phase 1: per-neighbor features for this lane's pair (2 pairs/wave).
  //      ee_kernel/ee_bias read directly (uniform -> scalar loads); fcut kept
  //      in a register for shfl-based distribution in beta. ----
  float my_fcut;
  {
    const int ph = l >> 5;       // which of the wave's two pairs
    const int n  = l & 31;
    const int p  = w * 2 + ph;   // pair-in-block 0..7
    const int bep = be0 + p;
    float rx = r[bep * 3 + 0];
    float ry = r[bep * 3 + 1];
    float rz = r[bep * 3 + 2];
    const float* rn = r_nb + (bep * NB + n) * 3;
    float dx = rn[0] - rx;
    float dy = rn[1] - ry;
    float dz = rn[2] - rz;
    float d2 = dx * dx + dy * dy + dz * dz;
    float dist = sqrtf(d2);
    float feats[4] = {dist, dx, dy, dz};
    float h[16];
    #pragma unroll
    for (int j = 0; j < 16; ++j) {
      float t = ee_bias[j];
      #pragma unroll
      for (int i = 0; i < 4; ++i) t += feats[i] * ee_kernel[i * F0 + j];
      h[j] = fast_tanh(t);
    }
    unsigned int hp0 = cvt_pk_bf16(h[0], h[1]);
    unsigned int hp1 = cvt_pk_bf16(h[2], h[3]);
    unsigned int hp2 = cvt_pk_bf16(h[4], h[5]);
    unsigned int hp3 = cvt_pk_bf16(h[6], h[7]);
    unsigned int hp4 = cvt_pk_bf16(h[8], h[9]);
    unsigned int hp5 = cvt_pk_bf16(h[10], h[11]);
    unsigned int hp6 = cvt_pk_bf16(h[12], h[13]);
    unsigned int hp7 = cvt_pk_bf16(h[14], h[15]);
    *(uint4*)&s_hb[p][0][n * 8] = make_uint4(hp0, hp1, hp2, hp3);
    *(uint4*)&s_hb[p][1][n * 8] = make_uint4(hp4, hp5, hp6, hp7);
    *(uint4*)&s_hb[p][3][n * 8] = make_uint4(0x3F80u, 0u, 0u, 0u);
    float env[NENV];
    #pragma unroll
    for (int s = 0; s < NENV; ++s) env[s] = __expf(-d2 * s_is2[s]);
    unsigned int e0 = cvt_pk_bf16(env[0], env[1]);
    unsigned int e1 = cvt_pk_bf16(env[2], env[3]);
    unsigned int e2 = cvt_pk_bf16(env[4], env[5]);
    unsigned int e3 = cvt_pk_bf16(env[6], env[7]);
    *(uint4*)&s_hb[p][2][n * 8] = make_uint4(e0, e1, e2, e3);
    float lp  = log1pf(dist);
    float inv = lp / dist;
    unsigned int q0 = cvt_pk_bf16(lp, dx * inv);
    unsigned int q1 = cvt_pk_bf16(dy * inv, dz * inv);
    *(uint4*)&s_inph[p][n * 8] = make_uint4(q0, q1, 0x3F80u, 0u);
    float xc = dist * (1.0f / CUT);
    my_fcut = (xc < 1.0f)
            ? 0.5f * (__cosf(3.14159265358979323846f * xc) + 1.0f)
            : 0.0f;
  }

  // ---- beta B-frags from global (pair-independent; same cvt sequence as the
  //      old LDS staging -> bit-identical). Lane holds chunk g, cols li/16+li. ----
  s16x8 bb0, bb1;
  {
    union { s16x8 v; unsigned int u[4]; } u0, u1;
    if (g < 3) {
      const float* bk0 = beta_kernel + (g * 8) * F1 + li;
      #pragma unroll
      for (int jj = 0; jj < 4; ++jj) {
        u0.u[jj] = cvt_pk_bf16(bk0[(2 * jj) * F1],      bk0[(2 * jj + 1) * F1]);
        u1.u[jj] = cvt_pk_bf16(bk0[(2 * jj) * F1 + 16], bk0[(2 * jj + 1) * F1 + 16]);
      }
    } else {
      u0.u[0] = cvt_pk_bf16(beta_bias[li], 0.0f);      u0.u[1] = u0.u[2] = u0.u[3] = 0u;
      u1.u[0] = cvt_pk_bf16(beta_bias[16 + li], 0.0f); u1.u[1] = u1.u[2] = u1.u[3] = 0u;
    }
    bb0 = u0.v; bb1 = u1.v;
  }

  // ---- beta via MFMA per pair: beta[n][c] = (hen @ bk + bias) * fcut[n].
  //      Wave-local read-then-overwrite of s_hb (r14-proven, no barrier).
  //      fcut fetched by shfl from the lane that computed it. ----
  auto beta_pair = [&](int p) {
    s16x8 ah0 = *(const s16x8*)&s_hb[p][g][(0 * 16 + li) * 8];
    s16x8 ah1 = *(const s16x8*)&s_hb[p][g][(1 * 16 + li) * 8];
    f32x4 z = {0.f, 0.f, 0.f, 0.f};
    f32x4 c00 = __builtin_amdgcn_mfma_f32_16x16x32_bf16(ah0, bb0, z, 0, 0, 0);
    f32x4 c01 = __builtin_amdgcn_mfma_f32_16x16x32_bf16(ah0, bb1, z, 0, 0, 0);
    f32x4 c10 = __builtin_amdgcn_mfma_f32_16x16x32_bf16(ah1, bb0, z, 0, 0, 0);
    f32x4 c11 = __builtin_amdgcn_mfma_f32_16x16x32_bf16(ah1, bb1, z, 0, 0, 0);
    const int cl = li >> 3;
    const int sl = li & 7;
    const int base = (p & 1) * 32;
    #pragma unroll
    for (int reg = 0; reg < 4; ++reg) {
      int row0 = g * 4 + reg;
      int row1 = 16 + g * 4 + reg;
      float fc0 = __shfl(my_fcut, base + row0);
      float fc1 = __shfl(my_fcut, base + row1);
      s_hb[p][cl    ][row0 * 8 + sl] = f2bf(c00[reg] * fc0);
      s_hb[p][2 + cl][row0 * 8 + sl] = f2bf(c01[reg] * fc0);
      s_hb[p][cl    ][row1 * 8 + sl] = f2bf(c10[reg] * fc1);
      s_hb[p][2 + cl][row1 * 8 + sl] = f2bf(c11[reg] * fc1);
    }
  };
  beta_pair(w * 2 + 0);
  beta_pair(w * 2 + 1);

  // ---- phase 2, PAIR-FUSED: one nt loop; gamma/d1k frags loaded once and
  //      shared by both pairs. A-frags register-consumed FIRST, then res rows
  //      overwrite the pairs' own s_inph rows (same-wave program-order DS;
  //      rows are pair-disjoint). Per-output accumulation order == r23. ----
  unsigned short* resall = &s_inph[0][0];   // [pair][RSTR] overlay
  {
    const int p0 = w * 2 + 0;
    const int p1 = w * 2 + 1;
    s16x8 a0_0 = *(const s16x8*)&s_hb[p0][g][(0 * 16 + li) * 8];
    s16x8 a1_0 = *(const s16x8*)&s_hb[p0][g][(1 * 16 + li) * 8];
    s16x8 ai0_0 = *(const s16x8*)&s_inph[p0][(0 * 16 + li) * 8];
    s16x8 ai1_0 = *(const s16x8*)&s_inph[p0][(1 * 16 + li) * 8];
    s16x8 a0_1 = *(const s16x8*)&s_hb[p1][g][(0 * 16 + li) * 8];
    s16x8 a1_1 = *(const s16x8*)&s_hb[p1][g][(1 * 16 + li) * 8];
    s16x8 ai0_1 = *(const s16x8*)&s_inph[p1][(0 * 16 + li) * 8];
    s16x8 ai1_1 = *(const s16x8*)&s_inph[p1][(1 * 16 + li) * 8];

    #pragma unroll 4
    for (int nt = 0; nt < 16; ++nt) {
      const int d = nt * 16 + li;
      s16x8 b = *(const s16x8*)&s_ghT[g][d * 8];
      union { s16x8 v; unsigned int u[4]; } ud;
      ud.u[0] = s_d1a[2 * d + 0];
      ud.u[1] = s_d1a[2 * d + 1];
      ud.u[2] = s_d1b[d];
      ud.u[3] = 0u;
      f32x4 z = {0.f, 0.f, 0.f, 0.f};
      // pair 0
      {
        f32x4 c0 = __builtin_amdgcn_mfma_f32_16x16x32_bf16(a0_0, b, z, 0, 0, 0);
        f32x4 c1 = __builtin_amdgcn_mfma_f32_16x16x32_bf16(a1_0, b, z, 0, 0, 0);
        f32x4 f0 = __builtin_amdgcn_mfma_f32_16x16x32_bf16(ai0_0, ud.v, z, 0, 0, 0);
        f32x4 f1 = __builtin_amdgcn_mfma_f32_16x16x32_bf16(ai1_0, ud.v, z, 0, 0, 0);
        float pv = 0.f;
        #pragma unroll
        for (int reg = 0; reg < 4; ++reg) {
          pv += silu(f0[reg]) * c0[reg];
          pv += silu(f1[reg]) * c1[reg];
        }
        pv += __shfl_xor(pv, 16);
        pv += __shfl_xor(pv, 32);
        if (g == (nt & 3)) resall[p0 * RSTR + nt * 16 + li] = f2bf(pv);
      }
      // pair 1
      {
        f32x4 c0 = __builtin_amdgcn_mfma_f32_16x16x32_bf16(a0_1, b, z, 0, 0, 0);
        f32x4 c1 = __builtin_amdgcn_mfma_f32_16x16x32_bf16(a1_1, b, z, 0, 0, 0);
        f32x4 f0 = __builtin_amdgcn_mfma_f32_16x16x32_bf16(ai0_1, ud.v, z, 0, 0, 0);
        f32x4 f1 = __builtin_amdgcn_mfma_f32_16x16x32_bf16(ai1_1, ud.v, z, 0, 0, 0);
        float pv = 0.f;
        #pragma unroll
        for (int reg = 0; reg < 4; ++reg) {
          pv += silu(f0[reg]) * c0[reg];
          pv += silu(f1[reg]) * c1[reg];
        }
        pv += __shfl_xor(pv, 16);
        pv += __shfl_xor(pv, 32);
        if (g == (nt & 3)) resall[p1 * RSTR + nt * 16 + li] = f2bf(pv);
      }
    }
  }

  __syncthreads();   // all 8 pairs' res rows needed by every wave in the tail

  // ---- tail: out[be0+0..7, :] = silu(res @ W + b). A rows = res[li&7]
  //      (8 real pairs, 2x replication); C rows g*4+reg written for g<2.
  //      B-frags via register PING-PONG, inline (no lambdas): ks+1's 32
  //      floats load into buf[(ks+1)&1] before ks's cvt+MFMA consumes
  //      buf[ks&1]. Fully-unrolled ks -> all buf indices compile-time
  //      constants -> mem2reg-promotable. Same addresses, cvt words, and
  //      acc/ks/nt order as r23 -> bit-identical. ----
  {
    const int col0 = w * 64;
    float bi[4];
    #pragma unroll
    for (int nt = 0; nt < 4; ++nt) bi[nt] = out_bias[col0 + nt * 16 + li];

    f32x4 acc[4] = {{0.f,0.f,0.f,0.f},{0.f,0.f,0.f,0.f},{0.f,0.f,0.f,0.f},{0.f,0.f,0.f,0.f}};
    const unsigned short* arow = resall + (li & 7) * RSTR + g * 8;
    const float* wp = out_kernel + col0 + li;   // lane's base column

    float buf[2][4][8];

    // prologue: ks=0 -> buf[0]
    #pragma unroll
    for (int nt = 0; nt < 4; ++nt) {
      const float* wq = wp + (0 * 32 + g * 8) * D + nt * 16;
      #pragma unroll
      for (int jj = 0; jj < 8; ++jj) buf[0][nt][jj] = wq[jj * D];
    }

    #pragma unroll
    for (int ks = 0; ks < 8; ++ks) {
      // prefetch ks+1 into the other buffer (program order: before consume)
      if (ks < 7) {
        #pragma unroll
        for (int nt = 0; nt < 4; ++nt) {
          const float* wq = wp + ((ks + 1) * 32 + g * 8) * D + nt * 16;
          #pragma unroll
          for (int jj = 0; jj < 8; ++jj) buf[(ks + 1) & 1][nt][jj] = wq[jj * D];
        }
      }
      // consume ks from buf[ks&1]
      s16x8 a = *(const s16x8*)(arow + ks * 32);
      #pragma unroll
      for (int nt = 0; nt < 4; ++nt) {
        union { s16x8 v; unsigned int u[4]; } ub;
        #pragma unroll
        for (int jj = 0; jj < 4; ++jj)
          ub.u[jj] = cvt_pk_bf16(buf[ks & 1][nt][2 * jj], buf[ks & 1][nt][2 * jj + 1]);
        acc[nt] = __builtin_amdgcn_mfma_f32_16x16x32_bf16(a, ub.v, acc[nt], 0, 0, 0);
      }
    }

    if (g < 2) {
      #pragma unroll
      for (int nt = 0; nt < 4; ++nt) {
        #pragma unroll
        for (int reg = 0; reg < 4; ++reg) {
          out[(be0 + g * 4 + reg) * D + col0 + nt * 16 + li] = silu(acc[nt][reg] + bi[nt]);
        }
      }
    }
  }
}

extern "C" void kernel_launch(void* const* d_in, const int* in_sizes, int n_in,
                              void* d_out, int out_size, void* d_ws, size_t ws_size,
                              hipStream_t stream) {
  const float* r            = (const float*)d_in[0];
  const float* r_nb         = (const float*)d_in[1];
  const float* ee_scales    = (const float*)d_in[2];
  const float* ee_kernel    = (const float*)d_in[3];
  const float* ee_bias      = (const float*)d_in[4];
  const float* beta_kernel  = (const float*)d_in[5];
  const float* beta_bias    = (const float*)d_in[6];
  const float* gamma_kernel = (const float*)d_in[7];
  const float* dense1_kernel= (const float*)d_in[8];
  const float* dense1_bias  = (const float*)d_in[9];
  const float* out_kernel   = (const float*)d_in[10];
  const float* out_bias     = (const float*)d_in[11];
  float* out = (float*)d_out;
  (void)d_ws; (void)ws_size;

  // single dispatch; 256 threads (harness convention); 8 pairs/block;
  // grid 1024 = 4 blocks/CU resident (LDS 40,224 B) -> one balanced round
  hipLaunchKernelGGL(moon_fused, dim3(PAIRS / 8), dim3(256), 0, stream,
                     r, r_nb, ee_scales, ee_kernel, ee_bias,
                     beta_kernel, beta_bias, gamma_kernel,
                     dense1_kernel, dense1_bias, out_kernel, out_bias, out);
}

// Round 15
// 109.910 us; speedup vs baseline: 1.1447x; 1.0025x over previous
//
#include <hip/hip_runtime.h>
#include <hip/hip_bf16.h>

constexpr int NB   = 32;
constexpr int NENV = 8;
constexpr int F0   = 16;
constexpr int F1   = 32;
constexpr int D    = 256;
constexpr int PAIRS = 128 * 64;   // 8192
constexpr float CUT = 5.0f;
constexpr int RSTR = 272;         // res-row stride in ushorts (544 B: 2-way banks)

typedef float f32x4 __attribute__((ext_vector_type(4)));
typedef short s16x8 __attribute__((ext_vector_type(8)));

__device__ __forceinline__ float fast_rcp(float x) { return __builtin_amdgcn_rcpf(x); }
__device__ __forceinline__ float silu(float a) {
  return a * fast_rcp(1.0f + __expf(-a));
}
__device__ __forceinline__ float fast_tanh(float t) {
  return 1.0f - 2.0f * fast_rcp(__expf(2.0f * t) + 1.0f);
}
// gfx950 single-instruction packed fp32->bf16 (RNE)
__device__ __forceinline__ unsigned int cvt_pk_bf16(float a, float b) {
  unsigned int r;
  asm("v_cvt_pk_bf16_f32 %0, %1, %2" : "=v"(r) : "v"(a), "v"(b));
  return r;
}
__device__ __forceinline__ unsigned short f2bf(float f) {
  return (unsigned short)(cvt_pk_bf16(f, f) & 0xffffu);
}

// ---------------------------------------------------------------------------
// r29 = r28 (verified 110.2 us; lambda-free tail ping-pong worked: moon_fused
// fell out of the rocprof top-5, <40.6 us/dispatch) + EARLY-ISSUE of the two
// remaining latency-exposed global loads:
//  - phase-1's r / r_nb (6 floats/lane) and the beta B-frag source floats
//    (16/lane) were issued at their consumption points, AFTER barriers --
//    the compiler cannot hoist global loads across __syncthreads(), so each
//    wave ate full L2/HBM latency there. Now both are issued at kernel entry
//    (ahead of the staging section's own gamma/d1k loads) into named
//    registers and consumed unchanged.
//  - ~22 extra VGPRs, under the 128 granted by waves_per_eu(4,4); LDS-capped
//    occupancy (4 blocks/CU, one balanced round at grid 1024) unaffected.
// Same values, same cvt_pk sequences, same accumulation order ->
// bit-identical output (absmax 0.09375).
//
// Verified-structure notes kept from r23/r28: 8 pairs/block at 256 threads
// (4 waves x 2 pairs), single dispatch; LDS 40,224 B; res-overlay stride 272;
// phase-2 pair-fused; tail register ping-pong (inline, no lambdas -- r26's
// regression was lambda array-ref params defeating mem2reg, rule-#20 class).
//
// HARNESS LAUNCH CONVENTION (empirical, r15-r20): single dispatch only, no
// d_ws, no module statics, block size 256. Grid size is respected.
// ---------------------------------------------------------------------------
__global__ __launch_bounds__(256)
__attribute__((amdgpu_waves_per_eu(4, 4)))
void moon_fused(
    const float* __restrict__ r,            // [8192,3]
    const float* __restrict__ r_nb,         // [8192,32,3]
    const float* __restrict__ ee_scales,    // [8]
    const float* __restrict__ ee_kernel,    // [4,16]
    const float* __restrict__ ee_bias,      // [16]
    const float* __restrict__ beta_kernel,  // [24,32]
    const float* __restrict__ beta_bias,    // [32]
    const float* __restrict__ gamma_kernel, // [32,256]
    const float* __restrict__ dense1_kernel,// [4,256]
    const float* __restrict__ dense1_bias,  // [256]
    const float* __restrict__ out_kernel,   // [256,256] (W[k][c], read in tail)
    const float* __restrict__ out_bias,     // [256]
    float* __restrict__ out)                // [8192,256]
{
  __shared__ unsigned short s_ghT[4][D * 8];    // [kslot g][d][8] bf16 (16384 B)
  __shared__ unsigned short s_hb[8][4][NB * 8]; // [pair][g][row][8] hen->beta (16384 B)
  __shared__ unsigned short s_inph[8][RSTR];    // [pair]: inp A-frags (first 256),
                                                // OVERLAID by res rows stride 272 (4352 B)
  __shared__ unsigned int s_d1a[2 * D];         // d1k frag words 0,1 (2048 B)
  __shared__ unsigned int s_d1b[D];             // d1k frag word 2   (1024 B)
  __shared__ float s_is2[NENV];                 // (32 B)
  // total: 40,224 B -> granule 40,448 -> 4 blocks/CU

  const int tid = threadIdx.x;
  const int w   = tid >> 6;                 // wave 0..3; wave w owns pairs 2w, 2w+1
  const int l   = tid & 63;
  const int be0 = blockIdx.x * 8;

  const int li = l & 15;          // col-within-tile
  const int g  = l >> 4;          // k-chunk / C-row group

  // ---- EARLY-ISSUE: phase-1 coordinates + beta-frag sources. Issued before
  //      the staging loads so their latency hides under staging conversion. ----
  const int ph_e  = l >> 5;       // which of the wave's two pairs
  const int n_e   = l & 31;
  const int p_e   = w * 2 + ph_e; // pair-in-block 0..7
  const int bep_e = be0 + p_e;
  const float rx = r[bep_e * 3 + 0];
  const float ry = r[bep_e * 3 + 1];
  const float rz = r[bep_e * 3 + 2];
  const float* rn_e = r_nb + (bep_e * NB + n_e) * 3;
  const float rnx = rn_e[0];
  const float rny = rn_e[1];
  const float rnz = rn_e[2];
  float bkv0[8], bkv1[8];
  if (g < 3) {
    const float* bk0 = beta_kernel + (g * 8) * F1 + li;
    #pragma unroll
    for (int jj = 0; jj < 8; ++jj) {
      bkv0[jj] = bk0[jj * F1];
      bkv1[jj] = bk0[jj * F1 + 16];
    }
  } else {
    bkv0[0] = beta_bias[li];
    bkv1[0] = beta_bias[16 + li];
  }

  // ---- staging: envelope scales (exact divide preserved) ----
  if (tid < 8) { float s = ee_scales[tid]; s_is2[tid] = 1.0f / (s * s); }

  // ---- staging: gamma -> bf16 transposed, k-chunked (thread t owns row d=t) ----
  {
    const int d = tid;
    unsigned int pk[16];
    #pragma unroll
    for (int k2 = 0; k2 < 16; ++k2)
      pk[k2] = cvt_pk_bf16(gamma_kernel[(2 * k2 + 0) * D + d],
                           gamma_kernel[(2 * k2 + 1) * D + d]);
    #pragma unroll
    for (int gg = 0; gg < 4; ++gg)
      *(uint4*)&s_ghT[gg][d * 8] = make_uint4(pk[4*gg], pk[4*gg+1], pk[4*gg+2], pk[4*gg+3]);
  }
  // ---- staging: d1k frag words, PRE-SCALED by 0.25 (replication cancel; exact) ----
  {
    const int d = tid;
    unsigned int p0 = cvt_pk_bf16(0.25f * dense1_kernel[0 * D + d],
                                  0.25f * dense1_kernel[1 * D + d]);
    unsigned int p1 = cvt_pk_bf16(0.25f * dense1_kernel[2 * D + d],
                                  0.25f * dense1_kernel[3 * D + d]);
    unsigned int p2 = cvt_pk_bf16(0.25f * dense1_bias[d], 0.0f);  // k=4; k=5..7 zero
    s_d1a[2 * d + 0] = p0;
    s_d1a[2 * d + 1] = p1;
    s_d1b[d] = p2;
  }

  __syncthreads();

  // ---- phase 1: per-neighbor features for this lane's pair (2 pairs/wave).
  //      Coordinates already in registers (early-issue); ee_kernel/ee_bias
  //      read directly (uniform -> scalar loads); fcut kept in a register
  //      for shfl-based distribution in beta. ----
  float my_fcut;
  {
    const int p = p_e;
    const int n = n_e;
    float dx = rnx - rx;
    float dy = rny - ry;
    float dz = rnz - rz;
    float d2 = dx * dx + dy * dy + dz * dz;
    float dist = sqrtf(d2);
    float feats[4] = {dist, dx, dy, dz};
    float h[16];
    #pragma unroll
    for (int j = 0; j < 16; ++j) {
      float t = ee_bias[j];
      #pragma unroll
      for (int i = 0; i < 4; ++i) t += feats[i] * ee_kernel[i * F0 + j];
      h[j] = fast_tanh(t);
    }
    unsigned int hp0 = cvt_pk_bf16(h[0], h[1]);
    unsigned int hp1 = cvt_pk_bf16(h[2], h[3]);
    unsigned int hp2 = cvt_pk_bf16(h[4], h[5]);
    unsigned int hp3 = cvt_pk_bf16(h[6], h[7]);
    unsigned int hp4 = cvt_pk_bf16(h[8], h[9]);
    unsigned int hp5 = cvt_pk_bf16(h[10], h[11]);
    unsigned int hp6 = cvt_pk_bf16(h[12], h[13]);
    unsigned int hp7 = cvt_pk_bf16(h[14], h[15]);
    *(uint4*)&s_hb[p][0][n * 8] = make_uint4(hp0, hp1, hp2, hp3);
    *(uint4*)&s_hb[p][1][n * 8] = make_uint4(hp4, hp5, hp6, hp7);
    *(uint4*)&s_hb[p][3][n * 8] = make_uint4(0x3F80u, 0u, 0u, 0u);
    float env[NENV];
    #pragma unroll
    for (int s = 0; s < NENV; ++s) env[s] = __expf(-d2 * s_is2[s]);
    unsigned int e0 = cvt_pk_bf16(env[0], env[1]);
    unsigned int e1 = cvt_pk_bf16(env[2], env[3]);
    unsigned int e2 = cvt_pk_bf16(env[4], env[5]);
    unsigned int e3 = cvt_pk_bf16(env[6], env[7]);
    *(uint4*)&s_hb[p][2][n * 8] = make_uint4(e0, e1, e2, e3);
    float lp  = log1pf(dist);
    float inv = lp / dist;
    unsigned int q0 = cvt_pk_bf16(lp, dx * inv);
    unsigned int q1 = cvt_pk_bf16(dy * inv, dz * inv);
    *(uint4*)&s_inph[p][n * 8] = make_uint4(q0, q1, 0x3F80u, 0u);
    float xc = dist * (1.0f / CUT);
    my_fcut = (xc < 1.0f)
            ? 0.5f * (__cosf(3.14159265358979323846f * xc) + 1.0f)
            : 0.0f;
  }

  // ---- beta B-frags from pre-loaded registers (same cvt sequence as the
  //      old LDS staging -> bit-identical). Lane holds chunk g, cols li/16+li. ----
  s16x8 bb0, bb1;
  {
    union { s16x8 v; unsigned int u[4]; } u0, u1;
    if (g < 3) {
      #pragma unroll
      for (int jj = 0; jj < 4; ++jj) {
        u0.u[jj] = cvt_pk_bf16(bkv0[2 * jj], bkv0[2 * jj + 1]);
        u1.u[jj] = cvt_pk_bf16(bkv1[2 * jj], bkv1[2 * jj + 1]);
      }
    } else {
      u0.u[0] = cvt_pk_bf16(bkv0[0], 0.0f); u0.u[1] = u0.u[2] = u0.u[3] = 0u;
      u1.u[0] = cvt_pk_bf16(bkv1[0], 0.0f); u1.u[1] = u1.u[2] = u1.u[3] = 0u;
    }
    bb0 = u0.v; bb1 = u1.v;
  }

  // ---- beta via MFMA per pair: beta[n][c] = (hen @ bk + bias) * fcut[n].
  //      Wave-local read-then-overwrite of s_hb (r14-proven, no barrier).
  //      fcut fetched by shfl from the lane that computed it. ----
  auto beta_pair = [&](int p) {
    s16x8 ah0 = *(const s16x8*)&s_hb[p][g][(0 * 16 + li) * 8];
    s16x8 ah1 = *(const s16x8*)&s_hb[p][g][(1 * 16 + li) * 8];
    f32x4 z = {0.f, 0.f, 0.f, 0.f};
    f32x4 c00 = __builtin_amdgcn_mfma_f32_16x16x32_bf16(ah0, bb0, z, 0, 0, 0);
    f32x4 c01 = __builtin_amdgcn_mfma_f32_16x16x32_bf16(ah0, bb1, z, 0, 0, 0);
    f32x4 c10 = __builtin_amdgcn_mfma_f32_16x16x32_bf16(ah1, bb0, z, 0, 0, 0);
    f32x4 c11 = __builtin_amdgcn_mfma_f32_16x16x32_bf16(ah1, bb1, z, 0, 0, 0);
    const int cl = li >> 3;
    const int sl = li & 7;
    const int base = (p & 1) * 32;
    #pragma unroll
    for (int reg = 0; reg < 4; ++reg) {
      int row0 = g * 4 + reg;
      int row1 = 16 + g * 4 + reg;
      float fc0 = __shfl(my_fcut, base + row0);
      float fc1 = __shfl(my_fcut, base + row1);
      s_hb[p][cl    ][row0 * 8 + sl] = f2bf(c00[reg] * fc0);
      s_hb[p][2 + cl][row0 * 8 + sl] = f2bf(c01[reg] * fc0);
      s_hb[p][cl    ][row1 * 8 + sl] = f2bf(c10[reg] * fc1);
      s_hb[p][2 + cl][row1 * 8 + sl] = f2bf(c11[reg] * fc1);
    }
  };
  beta_pair(w * 2 + 0);
  beta_pair(w * 2 + 1);

  // ---- phase 2, PAIR-FUSED: one nt loop; gamma/d1k frags loaded once and
  //      shared by both pairs. A-frags register-consumed FIRST, then res rows
  //      overwrite the pairs' own s_inph rows (same-wave program-order DS;
  //      rows are pair-disjoint). Per-output accumulation order == r23. ----
  unsigned short* resall = &s_inph[0][0];   // [pair][RSTR] overlay
  {
    const int p0 = w * 2 + 0;
    const int p1 = w * 2 + 1;
    s16x8 a0_0 = *(const s16x8*)&s_hb[p0][g][(0 * 16 + li) * 8];
    s16x8 a1_0 = *(const s16x8*)&s_hb[p0][g][(1 * 16 + li) * 8];
    s16x8 ai0_0 = *(const s16x8*)&s_inph[p0][(0 * 16 + li) * 8];
    s16x8 ai1_0 = *(const s16x8*)&s_inph[p0][(1 * 16 + li) * 8];
    s16x8 a0_1 = *(const s16x8*)&s_hb[p1][g][(0 * 16 + li) * 8];
    s16x8 a1_1 = *(const s16x8*)&s_hb[p1][g][(1 * 16 + li) * 8];
    s16x8 ai0_1 = *(const s16x8*)&s_inph[p1][(0 * 16 + li) * 8];
    s16x8 ai1_1 = *(const s16x8*)&s_inph[p1][(1 * 16 + li) * 8];

    #pragma unroll 4
    for (int nt = 0; nt < 16; ++nt) {
      const int d = nt * 16 + li;
      s16x8 b = *(const s16x8*)&s_ghT[g][d * 8];
      union { s16x8 v; unsigned int u[4]; } ud;
      ud.u[0] = s_d1a[2 * d + 0];
      ud.u[1] = s_d1a[2 * d + 1];
      ud.u[2] = s_d1b[d];
      ud.u[3] = 0u;
      f32x4 z = {0.f, 0.f, 0.f, 0.f};
      // pair 0
      {
        f32x4 c0 = __builtin_amdgcn_mfma_f32_16x16x32_bf16(a0_0, b, z, 0, 0, 0);
        f32x4 c1 = __builtin_amdgcn_mfma_f32_16x16x32_bf16(a1_0, b, z, 0, 0, 0);
        f32x4 f0 = __builtin_amdgcn_mfma_f32_16x16x32_bf16(ai0_0, ud.v, z, 0, 0, 0);
        f32x4 f1 = __builtin_amdgcn_mfma_f32_16x16x32_bf16(ai1_0, ud.v, z, 0, 0, 0);
        float pv = 0.f;
        #pragma unroll
        for (int reg = 0; reg < 4; ++reg) {
          pv += silu(f0[reg]) * c0[reg];
          pv += silu(f1[reg]) * c1[reg];
        }
        pv += __shfl_xor(pv, 16);
        pv += __shfl_xor(pv, 32);
        if (g == (nt & 3)) resall[p0 * RSTR + nt * 16 + li] = f2bf(pv);
      }
      // pair 1
      {
        f32x4 c0 = __builtin_amdgcn_mfma_f32_16x16x32_bf16(a0_1, b, z, 0, 0, 0);
        f32x4 c1 = __builtin_amdgcn_mfma_f32_16x16x32_bf16(a1_1, b, z, 0, 0, 0);
        f32x4 f0 = __builtin_amdgcn_mfma_f32_16x16x32_bf16(ai0_1, ud.v, z, 0, 0, 0);
        f32x4 f1 = __builtin_amdgcn_mfma_f32_16x16x32_bf16(ai1_1, ud.v, z, 0, 0, 0);
        float pv = 0.f;
        #pragma unroll
        for (int reg = 0; reg < 4; ++reg) {
          pv += silu(f0[reg]) * c0[reg];
          pv += silu(f1[reg]) * c1[reg];
        }
        pv += __shfl_xor(pv, 16);
        pv += __shfl_xor(pv, 32);
        if (g == (nt & 3)) resall[p1 * RSTR + nt * 16 + li] = f2bf(pv);
      }
    }
  }

  __syncthreads();   // all 8 pairs' res rows needed by every wave in the tail

  // ---- tail: out[be0+0..7, :] = silu(res @ W + b). A rows = res[li&7]
  //      (8 real pairs, 2x replication); C rows g*4+reg written for g<2.
  //      B-frags via register PING-PONG, inline (no lambdas): ks+1's 32
  //      floats load into buf[(ks+1)&1] before ks's cvt+MFMA consumes
  //      buf[ks&1]. Fully-unrolled ks -> all buf indices compile-time
  //      constants -> mem2reg-promotable. Same addresses, cvt words, and
  //      acc/ks/nt order as r23 -> bit-identical. ----
  {
    const int col0 = w * 64;
    float bi[4];
    #pragma unroll
    for (int nt = 0; nt < 4; ++nt) bi[nt] = out_bias[col0 + nt * 16 + li];

    f32x4 acc[4] = {{0.f,0.f,0.f,0.f},{0.f,0.f,0.f,0.f},{0.f,0.f,0.f,0.f},{0.f,0.f,0.f,0.f}};
    const unsigned short* arow = resall + (li & 7) * RSTR + g * 8;
    const float* wp = out_kernel + col0 + li;   // lane's base column

    float buf[2][4][8];

    // prologue: ks=0 -> buf[0]
    #pragma unroll
    for (int nt = 0; nt < 4; ++nt) {
      const float* wq = wp + (0 * 32 + g * 8) * D + nt * 16;
      #pragma unroll
      for (int jj = 0; jj < 8; ++jj) buf[0][nt][jj] = wq[jj * D];
    }

    #pragma unroll
    for (int ks = 0; ks < 8; ++ks) {
      // prefetch ks+1 into the other buffer (program order: before consume)
      if (ks < 7) {
        #pragma unroll
        for (int nt = 0; nt < 4; ++nt) {
          const float* wq = wp + ((ks + 1) * 32 + g * 8) * D + nt * 16;
          #pragma unroll
          for (int jj = 0; jj < 8; ++jj) buf[(ks + 1) & 1][nt][jj] = wq[jj * D];
        }
      }
      // consume ks from buf[ks&1]
      s16x8 a = *(const s16x8*)(arow + ks * 32);
      #pragma unroll
      for (int nt = 0; nt < 4; ++nt) {
        union { s16x8 v; unsigned int u[4]; } ub;
        #pragma unroll
        for (int jj = 0; jj < 4; ++jj)
          ub.u[jj] = cvt_pk_bf16(buf[ks & 1][nt][2 * jj], buf[ks & 1][nt][2 * jj + 1]);
        acc[nt] = __builtin_amdgcn_mfma_f32_16x16x32_bf16(a, ub.v, acc[nt], 0, 0, 0);
      }
    }

    if (g < 2) {
      #pragma unroll
      for (int nt = 0; nt < 4; ++nt) {
        #pragma unroll
        for (int reg = 0; reg < 4; ++reg) {
          out[(be0 + g * 4 + reg) * D + col0 + nt * 16 + li] = silu(acc[nt][reg] + bi[nt]);
        }
      }
    }
  }
}

extern "C" void kernel_launch(void* const* d_in, const int* in_sizes, int n_in,
                              void* d_out, int out_size, void* d_ws, size_t ws_size,
                              hipStream_t stream) {
  const float* r            = (const float*)d_in[0];
  const float* r_nb         = (const float*)d_in[1];
  const float* ee_scales    = (const float*)d_in[2];
  const float* ee_kernel    = (const float*)d_in[3];
  const float* ee_bias      = (const float*)d_in[4];
  const float* beta_kernel  = (const float*)d_in[5];
  const float* beta_bias    = (const float*)d_in[6];
  const float* gamma_kernel = (const float*)d_in[7];
  const float* dense1_kernel= (const float*)d_in[8];
  const float* dense1_bias  = (const float*)d_in[9];
  const float* out_kernel   = (const float*)d_in[10];
  const float* out_bias     = (const float*)d_in[11];
  float* out = (float*)d_out;
  (void)d_ws; (void)ws_size;

  // single dispatch; 256 threads (harness convention); 8 pairs/block;
  // grid 1024 = 4 blocks/CU resident (LDS 40,224 B) -> one balanced round
  hipLaunchKernelGGL(moon_fused, dim3(PAIRS / 8), dim3(256), 0, stream,
                     r, r_nb, ee_scales, ee_kernel, ee_bias,
                     beta_kernel, beta_bias, gamma_kernel,
                     dense1_kernel, dense1_bias, out_kernel, out_bias, out);
}